// Round 15
// baseline (1059.093 us; speedup 1.0000x reference)
//
#include <hip/hip_runtime.h>

#define SS 30
#define QQ 16
#define NV1 21
#define NV2 11
#define NVT 32
#define NBPB 4                 // batches per block (single wave, 2 rows/thread)
#define ROWS (NBPB * SS)       // 120
#define THREADS 64

#define LOG2E 1.44269504088896340736f

typedef float v2f __attribute__((ext_vector_type(2)));
typedef float v4f __attribute__((ext_vector_type(4)));
// unaligned views for direct global stores at 4-B granularity
typedef float v4fu __attribute__((ext_vector_type(4), aligned(4)));
typedef float v2fu __attribute__((ext_vector_type(2), aligned(4)));

__device__ __forceinline__ v2f bcast(float x) { v2f r; r.x = x; r.y = x; return r; }
__device__ __forceinline__ v2f pkfma(v2f a, v2f b, v2f c) {
    return __builtin_elementwise_fma(a, b, c);   // -> v_pk_fma_f32 on gfx950
}

// ---- kernel 1: one block precomputes weight-derived constants into ws ----
// ws layout (floats): [0..39] cm (log2e*M,w for both branches)
//                     [40..167] vwt as 32 x v4f (V weights * 2*log2e)
//                     [168..199] vbl (V bias * 2*log2e)
__global__ __launch_bounds__(64) void precompute_consts(
    const float* __restrict__ q1w, const float* __restrict__ q1b,
    const float* __restrict__ k1w,
    const float* __restrict__ q2w, const float* __restrict__ q2b,
    const float* __restrict__ k2w,
    const float* __restrict__ v1w, const float* __restrict__ v1b,
    const float* __restrict__ v2w, const float* __restrict__ v2b,
    float* __restrict__ ws)
{
    const int tid = threadIdx.x;
    if (tid < 40) {
        const int br = tid / 20, idx = tid % 20;
        const float* qw = br ? q2w : q1w;
        const float* qb = br ? q2b : q1b;
        const float* kw = br ? k2w : k1w;
        float acc = 0.f;
        if (idx < 16) {
            const int d = idx >> 2, e = idx & 3;
            #pragma unroll
            for (int q = 0; q < QQ; ++q) acc += qw[d * QQ + q] * kw[e * QQ + q];
        } else {
            const int e = idx - 16;
            #pragma unroll
            for (int q = 0; q < QQ; ++q) acc += kw[e * QQ + q] * qb[q];
        }
        ws[tid] = acc * LOG2E;
    }
    if (tid < NVT) {
        const float s2l = 2.0f * LOG2E;
        v4f w; float b;
        if (tid < NV1) {
            w.x = v1w[tid] * s2l;          w.y = v1w[NV1 + tid] * s2l;
            w.z = v1w[2 * NV1 + tid] * s2l; w.w = v1w[3 * NV1 + tid] * s2l;
            b = v1b[tid] * s2l;
        } else {
            const int p = tid - NV1;
            w.x = v2w[p] * s2l;            w.y = v2w[NV2 + p] * s2l;
            w.z = v2w[2 * NV2 + p] * s2l;  w.w = v2w[3 * NV2 + p] * s2l;
            b = v2b[p] * s2l;
        }
        reinterpret_cast<v4f*>(ws + 40)[tid] = w;
        ws[168 + tid] = b;
    }
}

// tanh epilogue helper: input v is pre-scaled by 2*log2e
__device__ __forceinline__ float tanh_fold(float v) {
    const float ex = __builtin_amdgcn_exp2f(v);
    return fmaf(-2.0f, __builtin_amdgcn_rcpf(ex + 1.0f), 1.0f);
}

// ---- kernel 2: single-wave blocks, no LDS, direct nt stores from registers ----
__global__ __launch_bounds__(THREADS, 4) void fused_dual_attn(
    const float* __restrict__ x, const float* __restrict__ ws,
    float* __restrict__ out1, float* __restrict__ out2)
{
    const int tid = threadIdx.x;
    const long long blk = blockIdx.x;
    const v4f* xgv = reinterpret_cast<const v4f*>(x) + blk * ROWS;

    if (tid >= 60) return;

    const int batch = (unsigned)tid / 15;
    const int sA = tid - batch * 15;
    const int rowA = batch * SS + sA;
    const int rowB = rowA + 15;
    const int boff = batch * SS;
    const v4f xra = xgv[rowA];
    const v4f xrb = xgv[rowB];

    v2f gA[4], gB[4];
    #pragma unroll
    for (int e = 0; e < 4; ++e) {
        gA[e].x = ws[16 + e] + xra.x * ws[e] + xra.y * ws[4 + e]
                + xra.z * ws[8 + e] + xra.w * ws[12 + e];
        gA[e].y = ws[36 + e] + xra.x * ws[20 + e] + xra.y * ws[24 + e]
                + xra.z * ws[28 + e] + xra.w * ws[32 + e];
        gB[e].x = ws[16 + e] + xrb.x * ws[e] + xrb.y * ws[4 + e]
                + xrb.z * ws[8 + e] + xrb.w * ws[12 + e];
        gB[e].y = ws[36 + e] + xrb.x * ws[20 + e] + xrb.y * ws[24 + e]
                + xrb.z * ws[28 + e] + xrb.w * ws[32 + e];
    }

    v2f hA[4] = {{0.f,0.f},{0.f,0.f},{0.f,0.f},{0.f,0.f}};
    v2f hB[4] = {{0.f,0.f},{0.f,0.f},{0.f,0.f},{0.f,0.f}};
    v2f sumA = {0.f, 0.f}, sumB = {0.f, 0.f};
    #pragma unroll
    for (int t = 0; t < SS; ++t) {
        const v4f xt = xgv[boff + t];      // L1-resident, 4-addr broadcast
        const v2f bx = bcast(xt.x), by = bcast(xt.y), bz = bcast(xt.z), bw = bcast(xt.w);
        v2f sA2 = gA[3] * bw;
        sA2 = pkfma(gA[2], bz, sA2);
        sA2 = pkfma(gA[1], by, sA2);
        sA2 = pkfma(gA[0], bx, sA2);
        v2f sB2 = gB[3] * bw;
        sB2 = pkfma(gB[2], bz, sB2);
        sB2 = pkfma(gB[1], by, sB2);
        sB2 = pkfma(gB[0], bx, sB2);
        v2f pA, pB;
        pA.x = __builtin_amdgcn_exp2f(sA2.x);
        pA.y = __builtin_amdgcn_exp2f(sA2.y);
        pB.x = __builtin_amdgcn_exp2f(sB2.x);
        pB.y = __builtin_amdgcn_exp2f(sB2.y);
        sumA = sumA + pA;
        sumB = sumB + pB;
        hA[0] = pkfma(pA, bx, hA[0]);
        hA[1] = pkfma(pA, by, hA[1]);
        hA[2] = pkfma(pA, bz, hA[2]);
        hA[3] = pkfma(pA, bw, hA[3]);
        hB[0] = pkfma(pB, bx, hB[0]);
        hB[1] = pkfma(pB, by, hB[1]);
        hB[2] = pkfma(pB, bz, hB[2]);
        hB[3] = pkfma(pB, bw, hB[3]);
    }
    v2f invA, invB;
    invA.x = __builtin_amdgcn_rcpf(sumA.x);
    invA.y = __builtin_amdgcn_rcpf(sumA.y);
    invB.x = __builtin_amdgcn_rcpf(sumB.x);
    invB.y = __builtin_amdgcn_rcpf(sumB.y);
    #pragma unroll
    for (int e = 0; e < 4; ++e) { hA[e] = hA[e] * invA; hB[e] = hB[e] * invB; }

    // repack: q1[e] = (hA[e].br1, hB[e].br1), q2[e] = (hA[e].br2, hB[e].br2)
    v2f q1[4], q2[4];
    #pragma unroll
    for (int e = 0; e < 4; ++e) {
        q1[e].x = hA[e].x; q1[e].y = hB[e].x;
        q2[e].x = hA[e].y; q2[e].y = hB[e].y;
    }

    // ---- branch-1: direct nt stores, v4f chunks (L2 write-combines rows) ----
    {
        float* o1A = out1 + (blk * ROWS + rowA) * NV1;
        float* o1B = out1 + (blk * ROWS + rowB) * NV1;
        #pragma unroll
        for (int c = 0; c < 5; ++c) {
            v4f cA, cB;
            #pragma unroll
            for (int j = 0; j < 4; ++j) {
                const int o = 4 * c + j;
                v2f v = bcast(ws[168 + o]);
                v = pkfma(q1[0], bcast(ws[40 + 4 * o + 0]), v);
                v = pkfma(q1[1], bcast(ws[40 + 4 * o + 1]), v);
                v = pkfma(q1[2], bcast(ws[40 + 4 * o + 2]), v);
                v = pkfma(q1[3], bcast(ws[40 + 4 * o + 3]), v);
                cA[j] = tanh_fold(v.x);
                cB[j] = tanh_fold(v.y);
            }
            __builtin_nontemporal_store(cA, reinterpret_cast<v4fu*>(o1A + 4 * c));
            __builtin_nontemporal_store(cB, reinterpret_cast<v4fu*>(o1B + 4 * c));
        }
        {   // o = 20 scalar tail
            const int o = 20;
            v2f v = bcast(ws[168 + o]);
            v = pkfma(q1[0], bcast(ws[40 + 4 * o + 0]), v);
            v = pkfma(q1[1], bcast(ws[40 + 4 * o + 1]), v);
            v = pkfma(q1[2], bcast(ws[40 + 4 * o + 2]), v);
            v = pkfma(q1[3], bcast(ws[40 + 4 * o + 3]), v);
            __builtin_nontemporal_store(tanh_fold(v.x), o1A + o);
            __builtin_nontemporal_store(tanh_fold(v.y), o1B + o);
        }
    }

    // ---- branch-2: 11 outputs = 2x v4f + v2f + scalar per row ----
    {
        float* o2A = out2 + (blk * ROWS + rowA) * NV2;
        float* o2B = out2 + (blk * ROWS + rowB) * NV2;
        #pragma unroll
        for (int c = 0; c < 2; ++c) {
            v4f cA, cB;
            #pragma unroll
            for (int j = 0; j < 4; ++j) {
                const int oo = NV1 + 4 * c + j;
                v2f v = bcast(ws[168 + oo]);
                v = pkfma(q2[0], bcast(ws[40 + 4 * oo + 0]), v);
                v = pkfma(q2[1], bcast(ws[40 + 4 * oo + 1]), v);
                v = pkfma(q2[2], bcast(ws[40 + 4 * oo + 2]), v);
                v = pkfma(q2[3], bcast(ws[40 + 4 * oo + 3]), v);
                cA[j] = tanh_fold(v.x);
                cB[j] = tanh_fold(v.y);
            }
            __builtin_nontemporal_store(cA, reinterpret_cast<v4fu*>(o2A + 4 * c));
            __builtin_nontemporal_store(cB, reinterpret_cast<v4fu*>(o2B + 4 * c));
        }
        {   // o = 8,9 as v2f
            v2f cA, cB;
            #pragma unroll
            for (int j = 0; j < 2; ++j) {
                const int oo = NV1 + 8 + j;
                v2f v = bcast(ws[168 + oo]);
                v = pkfma(q2[0], bcast(ws[40 + 4 * oo + 0]), v);
                v = pkfma(q2[1], bcast(ws[40 + 4 * oo + 1]), v);
                v = pkfma(q2[2], bcast(ws[40 + 4 * oo + 2]), v);
                v = pkfma(q2[3], bcast(ws[40 + 4 * oo + 3]), v);
                cA[j] = tanh_fold(v.x);
                cB[j] = tanh_fold(v.y);
            }
            __builtin_nontemporal_store(cA, reinterpret_cast<v2fu*>(o2A + 8));
            __builtin_nontemporal_store(cB, reinterpret_cast<v2fu*>(o2B + 8));
        }
        {   // o = 10 scalar tail
            const int oo = NV1 + 10;
            v2f v = bcast(ws[168 + oo]);
            v = pkfma(q2[0], bcast(ws[40 + 4 * oo + 0]), v);
            v = pkfma(q2[1], bcast(ws[40 + 4 * oo + 1]), v);
            v = pkfma(q2[2], bcast(ws[40 + 4 * oo + 2]), v);
            v = pkfma(q2[3], bcast(ws[40 + 4 * oo + 3]), v);
            __builtin_nontemporal_store(tanh_fold(v.x), o2A + 10);
            __builtin_nontemporal_store(tanh_fold(v.y), o2B + 10);
        }
    }
}

extern "C" void kernel_launch(void* const* d_in, const int* in_sizes, int n_in,
                              void* d_out, int out_size, void* d_ws, size_t ws_size,
                              hipStream_t stream) {
    const float* x   = (const float*)d_in[0];
    const float* q1w = (const float*)d_in[1];
    const float* q1b = (const float*)d_in[2];
    const float* k1w = (const float*)d_in[3];
    const float* v1w = (const float*)d_in[5];
    const float* v1b = (const float*)d_in[6];
    const float* q2w = (const float*)d_in[7];
    const float* q2b = (const float*)d_in[8];
    const float* k2w = (const float*)d_in[9];
    const float* v2w = (const float*)d_in[11];
    const float* v2b = (const float*)d_in[12];

    const long long B = 131072LL;
    float* out1 = (float*)d_out;
    float* out2 = out1 + B * SS * NV1;
    float* ws   = (float*)d_ws;

    precompute_consts<<<1, 64, 0, stream>>>(q1w, q1b, k1w, q2w, q2b, k2w,
                                            v1w, v1b, v2w, v2b, ws);

    const int nblocks = (int)(B / NBPB);  // 32768
    fused_dual_attn<<<nblocks, THREADS, 0, stream>>>(x, ws, out1, out2);
}

// Round 16
// 129.120 us; speedup vs baseline: 8.2024x; 8.2024x over previous
//
#include <hip/hip_runtime.h>

#define SS 30
#define QQ 16
#define NV1 21
#define NV2 11
#define NVT 32
#define NBPB 4                 // batches per block (single wave, 2 rows/thread)
#define ROWS (NBPB * SS)       // 120
#define THREADS 64

#define LOG2E 1.44269504088896340736f

typedef float v2f __attribute__((ext_vector_type(2)));
typedef float v4f __attribute__((ext_vector_type(4)));

__device__ __forceinline__ v2f bcast(float x) { v2f r; r.x = x; r.y = x; return r; }
__device__ __forceinline__ v2f pkfma(v2f a, v2f b, v2f c) {
    return __builtin_elementwise_fma(a, b, c);   // -> v_pk_fma_f32 on gfx950
}

// ---- kernel 1: one block precomputes weight-derived constants into ws ----
// ws layout (floats): [0..39] cm (log2e*M,w for both branches)
//                     [40..167] vwt as 32 x v4f (V weights * 2*log2e)
//                     [168..199] vbl (V bias * 2*log2e)
__global__ __launch_bounds__(64) void precompute_consts(
    const float* __restrict__ q1w, const float* __restrict__ q1b,
    const float* __restrict__ k1w,
    const float* __restrict__ q2w, const float* __restrict__ q2b,
    const float* __restrict__ k2w,
    const float* __restrict__ v1w, const float* __restrict__ v1b,
    const float* __restrict__ v2w, const float* __restrict__ v2b,
    float* __restrict__ ws)
{
    const int tid = threadIdx.x;
    if (tid < 40) {
        const int br = tid / 20, idx = tid % 20;
        const float* qw = br ? q2w : q1w;
        const float* qb = br ? q2b : q1b;
        const float* kw = br ? k2w : k1w;
        float acc = 0.f;
        if (idx < 16) {
            const int d = idx >> 2, e = idx & 3;
            #pragma unroll
            for (int q = 0; q < QQ; ++q) acc += qw[d * QQ + q] * kw[e * QQ + q];
        } else {
            const int e = idx - 16;
            #pragma unroll
            for (int q = 0; q < QQ; ++q) acc += kw[e * QQ + q] * qb[q];
        }
        ws[tid] = acc * LOG2E;
    }
    if (tid < NVT) {
        const float s2l = 2.0f * LOG2E;
        v4f w; float b;
        if (tid < NV1) {
            w.x = v1w[tid] * s2l;          w.y = v1w[NV1 + tid] * s2l;
            w.z = v1w[2 * NV1 + tid] * s2l; w.w = v1w[3 * NV1 + tid] * s2l;
            b = v1b[tid] * s2l;
        } else {
            const int p = tid - NV1;
            w.x = v2w[p] * s2l;            w.y = v2w[NV2 + p] * s2l;
            w.z = v2w[2 * NV2 + p] * s2l;  w.w = v2w[3 * NV2 + p] * s2l;
            b = v2b[p] * s2l;
        }
        reinterpret_cast<v4f*>(ws + 40)[tid] = w;
        ws[168 + tid] = b;
    }
}

// ---- kernel 2: single-wave blocks, 4 batches, 2 rows/thread (same batch) ----
__global__ __launch_bounds__(THREADS, 4) void fused_dual_attn(
    const float* __restrict__ x, const float* __restrict__ ws,
    float* __restrict__ out1, float* __restrict__ out2)
{
    __shared__ alignas(16) float stage[ROWS * NV1];  // 10.08 KB, only LDS user

    const int tid = threadIdx.x;
    const long long blk = blockIdx.x;
    const v4f* xgv = reinterpret_cast<const v4f*>(x) + blk * ROWS;

    // per-thread state: rows rA = batch*30 + s, rB = rA + 15 (same batch)
    // v2f lanes pack (branch1, branch2) for each row
    v2f hA[4] = {{0.f,0.f},{0.f,0.f},{0.f,0.f},{0.f,0.f}};
    v2f hB[4] = {{0.f,0.f},{0.f,0.f},{0.f,0.f},{0.f,0.f}};
    int rowA = 0, rowB = 0;

    if (tid < 60) {
        const int batch = (unsigned)tid / 15;
        const int sA = tid - batch * 15;
        rowA = batch * SS + sA;
        rowB = rowA + 15;
        const int boff = batch * SS;
        const v4f xra = xgv[rowA];
        const v4f xrb = xgv[rowB];

        // g vectors from scalar-cached constants (compile-time ws indices)
        v2f gA[4], gB[4];
        #pragma unroll
        for (int e = 0; e < 4; ++e) {
            gA[e].x = ws[16 + e] + xra.x * ws[e] + xra.y * ws[4 + e]
                    + xra.z * ws[8 + e] + xra.w * ws[12 + e];
            gA[e].y = ws[36 + e] + xra.x * ws[20 + e] + xra.y * ws[24 + e]
                    + xra.z * ws[28 + e] + xra.w * ws[32 + e];
            gB[e].x = ws[16 + e] + xrb.x * ws[e] + xrb.y * ws[4 + e]
                    + xrb.z * ws[8 + e] + xrb.w * ws[12 + e];
            gB[e].y = ws[36 + e] + xrb.x * ws[20 + e] + xrb.y * ws[24 + e]
                    + xrb.z * ws[28 + e] + xrb.w * ws[32 + e];
        }

        v2f sumA = {0.f, 0.f}, sumB = {0.f, 0.f};
        #pragma unroll
        for (int t = 0; t < SS; ++t) {
            const v4f xt = xgv[boff + t];      // L1-resident, 4-addr broadcast
            const v2f bx = bcast(xt.x), by = bcast(xt.y), bz = bcast(xt.z), bw = bcast(xt.w);
            v2f sA2 = gA[3] * bw;
            sA2 = pkfma(gA[2], bz, sA2);
            sA2 = pkfma(gA[1], by, sA2);
            sA2 = pkfma(gA[0], bx, sA2);
            v2f sB2 = gB[3] * bw;
            sB2 = pkfma(gB[2], bz, sB2);
            sB2 = pkfma(gB[1], by, sB2);
            sB2 = pkfma(gB[0], bx, sB2);
            v2f pA, pB;
            pA.x = __builtin_amdgcn_exp2f(sA2.x);
            pA.y = __builtin_amdgcn_exp2f(sA2.y);
            pB.x = __builtin_amdgcn_exp2f(sB2.x);
            pB.y = __builtin_amdgcn_exp2f(sB2.y);
            sumA = sumA + pA;
            sumB = sumB + pB;
            hA[0] = pkfma(pA, bx, hA[0]);
            hA[1] = pkfma(pA, by, hA[1]);
            hA[2] = pkfma(pA, bz, hA[2]);
            hA[3] = pkfma(pA, bw, hA[3]);
            hB[0] = pkfma(pB, bx, hB[0]);
            hB[1] = pkfma(pB, by, hB[1]);
            hB[2] = pkfma(pB, bz, hB[2]);
            hB[3] = pkfma(pB, bw, hB[3]);
        }
        v2f invA, invB;
        invA.x = __builtin_amdgcn_rcpf(sumA.x);
        invA.y = __builtin_amdgcn_rcpf(sumA.y);
        invB.x = __builtin_amdgcn_rcpf(sumB.x);
        invB.y = __builtin_amdgcn_rcpf(sumB.y);
        #pragma unroll
        for (int e = 0; e < 4; ++e) { hA[e] = hA[e] * invA; hB[e] = hB[e] * invB; }
    }

    // branch-1 epilogue: scalar V-projection + tanh (weights stay in SGPRs)
    if (tid < 60) {
        float* spA = stage + rowA * NV1;
        float* spB = stage + rowB * NV1;
        #pragma unroll
        for (int o = 0; o < NV1; ++o) {
            float vA = ws[168 + o];
            vA = fmaf(hA[0].x, ws[40 + 4 * o + 0], vA);
            vA = fmaf(hA[1].x, ws[40 + 4 * o + 1], vA);
            vA = fmaf(hA[2].x, ws[40 + 4 * o + 2], vA);
            vA = fmaf(hA[3].x, ws[40 + 4 * o + 3], vA);
            const float exA = __builtin_amdgcn_exp2f(vA);
            spA[o] = fmaf(-2.0f, __builtin_amdgcn_rcpf(exA + 1.0f), 1.0f);
            float vB = ws[168 + o];
            vB = fmaf(hB[0].x, ws[40 + 4 * o + 0], vB);
            vB = fmaf(hB[1].x, ws[40 + 4 * o + 1], vB);
            vB = fmaf(hB[2].x, ws[40 + 4 * o + 2], vB);
            vB = fmaf(hB[3].x, ws[40 + 4 * o + 3], vB);
            const float exB = __builtin_amdgcn_exp2f(vB);
            spB[o] = fmaf(-2.0f, __builtin_amdgcn_rcpf(exB + 1.0f), 1.0f);
        }
    }
    __syncthreads();
    {
        const int n1 = ROWS * NV1 / 4;   // 630
        v4f* dst1 = reinterpret_cast<v4f*>(out1) + blk * n1;
        const v4f* src = reinterpret_cast<const v4f*>(stage);
        #pragma unroll
        for (int k = 0; k < n1 / THREADS; ++k)
            __builtin_nontemporal_store(src[k * THREADS + tid], dst1 + k * THREADS + tid);
        {   // remainder 630 - 9*64 = 54
            const int i = (n1 / THREADS) * THREADS + tid;
            if (i < n1) __builtin_nontemporal_store(src[i], dst1 + i);
        }
    }
    __syncthreads();

    // branch-2 epilogue (stage buffer reused)
    if (tid < 60) {
        float* spA = stage + rowA * NV2;
        float* spB = stage + rowB * NV2;
        #pragma unroll
        for (int o = 0; o < NV2; ++o) {
            const int oo = NV1 + o;
            float vA = ws[168 + oo];
            vA = fmaf(hA[0].y, ws[40 + 4 * oo + 0], vA);
            vA = fmaf(hA[1].y, ws[40 + 4 * oo + 1], vA);
            vA = fmaf(hA[2].y, ws[40 + 4 * oo + 2], vA);
            vA = fmaf(hA[3].y, ws[40 + 4 * oo + 3], vA);
            const float exA = __builtin_amdgcn_exp2f(vA);
            spA[o] = fmaf(-2.0f, __builtin_amdgcn_rcpf(exA + 1.0f), 1.0f);
            float vB = ws[168 + oo];
            vB = fmaf(hB[0].y, ws[40 + 4 * oo + 0], vB);
            vB = fmaf(hB[1].y, ws[40 + 4 * oo + 1], vB);
            vB = fmaf(hB[2].y, ws[40 + 4 * oo + 2], vB);
            vB = fmaf(hB[3].y, ws[40 + 4 * oo + 3], vB);
            const float exB = __builtin_amdgcn_exp2f(vB);
            spB[o] = fmaf(-2.0f, __builtin_amdgcn_rcpf(exB + 1.0f), 1.0f);
        }
    }
    __syncthreads();
    {
        const int n2 = ROWS * NV2 / 4;   // 330
        v4f* dst2 = reinterpret_cast<v4f*>(out2) + blk * n2;
        const v4f* src = reinterpret_cast<const v4f*>(stage);
        #pragma unroll
        for (int k = 0; k < n2 / THREADS; ++k)
            __builtin_nontemporal_store(src[k * THREADS + tid], dst2 + k * THREADS + tid);
        {   // remainder 330 - 5*64 = 10
            const int i = (n2 / THREADS) * THREADS + tid;
            if (i < n2) __builtin_nontemporal_store(src[i], dst2 + i);
        }
    }
}

extern "C" void kernel_launch(void* const* d_in, const int* in_sizes, int n_in,
                              void* d_out, int out_size, void* d_ws, size_t ws_size,
                              hipStream_t stream) {
    const float* x   = (const float*)d_in[0];
    const float* q1w = (const float*)d_in[1];
    const float* q1b = (const float*)d_in[2];
    const float* k1w = (const float*)d_in[3];
    const float* v1w = (const float*)d_in[5];
    const float* v1b = (const float*)d_in[6];
    const float* q2w = (const float*)d_in[7];
    const float* q2b = (const float*)d_in[8];
    const float* k2w = (const float*)d_in[9];
    const float* v2w = (const float*)d_in[11];
    const float* v2b = (const float*)d_in[12];

    const long long B = 131072LL;
    float* out1 = (float*)d_out;
    float* out2 = out1 + B * SS * NV1;
    float* ws   = (float*)d_ws;

    precompute_consts<<<1, 64, 0, stream>>>(q1w, q1b, k1w, q2w, q2b, k2w,
                                            v1w, v1b, v2w, v2b, ws);

    const int nblocks = (int)(B / NBPB);  // 32768
    fused_dual_attn<<<nblocks, THREADS, 0, stream>>>(x, ws, out1, out2);
}